// Round 1
// baseline (1385.571 us; speedup 1.0000x reference)
//
#include <hip/hip_runtime.h>

#define NN 100000
#define NE 1600000
#define NG 256
#define EPT 4
#define NPT 2

__device__ __forceinline__ unsigned fenc(float f) {
    unsigned u = __float_as_uint(f);
    return (u & 0x80000000u) ? ~u : (u | 0x80000000u);
}
__device__ __forceinline__ float fdec(unsigned e) {
    return __uint_as_float((e & 0x80000000u) ? (e & 0x7FFFFFFFu) : ~e);
}

__global__ __launch_bounds__(256) void zero_kernel(float* __restrict__ p, int n) {
    int i = blockIdx.x * 256 + threadIdx.x;
    if (i < n) p[i] = 0.f;
}

// Edge MLP: in = [x[row](7), x[col](7), ea(3)] -> relu(in@W1+b1) @ W2 + b2 -> ea'
// plus scatter add/max/count into per-node accumulators keyed by col.
__global__ __launch_bounds__(256) void edge_kernel(
    const float* __restrict__ x, const float* __restrict__ ein,
    float* __restrict__ eout,
    const int* __restrict__ row, const int* __restrict__ col,
    const float* __restrict__ W1, const float* __restrict__ b1,
    const float* __restrict__ W2, const float* __restrict__ b2,
    float* __restrict__ nsum, unsigned* __restrict__ nmax,
    float* __restrict__ ncnt, int count_flag)
{
    // LDS layout: per hidden unit j a padded row of 20 floats:
    // [W1[0..16][j], b1[j], pad, pad]; and W2 row j padded to 4.
    __shared__ __align__(16) float sW1T[128 * 20];
    __shared__ __align__(16) float sW2p[128 * 4];
    int tid = threadIdx.x;
    for (int t = tid; t < 17 * 128; t += 256) { int i = t >> 7, j = t & 127; sW1T[j * 20 + i] = W1[t]; }
    for (int t = tid; t < 128; t += 256) sW1T[t * 20 + 17] = b1[t];
    for (int t = tid; t < 384; t += 256) { int j = t / 3, k = t - j * 3; sW2p[j * 4 + k] = W2[t]; }
    __syncthreads();

    float in[EPT][17];
    float acc[EPT][3];
    int cols[EPT];
    int e0 = blockIdx.x * (256 * EPT) + tid;

    #pragma unroll
    for (int k = 0; k < EPT; ++k) {
        int e = e0 + k * 256;
        if (e < NE) {
            int r = row[e], c = col[e];
            cols[k] = c;
            #pragma unroll
            for (int i = 0; i < 7; ++i) in[k][i] = x[r * 7 + i];
            #pragma unroll
            for (int i = 0; i < 7; ++i) in[k][7 + i] = x[c * 7 + i];
            #pragma unroll
            for (int i = 0; i < 3; ++i) in[k][14 + i] = ein[e * 3 + i];
        } else {
            cols[k] = -1;
            #pragma unroll
            for (int i = 0; i < 17; ++i) in[k][i] = 0.f;
        }
        acc[k][0] = acc[k][1] = acc[k][2] = 0.f;
    }

    for (int j = 0; j < 128; ++j) {
        float4 w0 = *(const float4*)&sW1T[j * 20 + 0];
        float4 w1 = *(const float4*)&sW1T[j * 20 + 4];
        float4 w2 = *(const float4*)&sW1T[j * 20 + 8];
        float4 w3 = *(const float4*)&sW1T[j * 20 + 12];
        float4 w4 = *(const float4*)&sW1T[j * 20 + 16]; // w16, b1, pad, pad
        float4 v2 = *(const float4*)&sW2p[j * 4];       // w2_0, w2_1, w2_2, pad
        #pragma unroll
        for (int k = 0; k < EPT; ++k) {
            float h = w4.y;
            h += in[k][0] * w0.x;  h += in[k][1] * w0.y;  h += in[k][2] * w0.z;  h += in[k][3] * w0.w;
            h += in[k][4] * w1.x;  h += in[k][5] * w1.y;  h += in[k][6] * w1.z;  h += in[k][7] * w1.w;
            h += in[k][8] * w2.x;  h += in[k][9] * w2.y;  h += in[k][10] * w2.z; h += in[k][11] * w2.w;
            h += in[k][12] * w3.x; h += in[k][13] * w3.y; h += in[k][14] * w3.z; h += in[k][15] * w3.w;
            h += in[k][16] * w4.x;
            h = fmaxf(h, 0.f);
            acc[k][0] += h * v2.x; acc[k][1] += h * v2.y; acc[k][2] += h * v2.z;
        }
    }

    float bb0 = b2[0], bb1 = b2[1], bb2 = b2[2];
    #pragma unroll
    for (int k = 0; k < EPT; ++k) {
        int e = e0 + k * 256;
        if (e < NE) {
            int c = cols[k];
            float o0 = acc[k][0] + bb0, o1 = acc[k][1] + bb1, o2 = acc[k][2] + bb2;
            eout[e * 3 + 0] = o0; eout[e * 3 + 1] = o1; eout[e * 3 + 2] = o2;
            atomicAdd(&nsum[c * 3 + 0], o0);
            atomicAdd(&nsum[c * 3 + 1], o1);
            atomicAdd(&nsum[c * 3 + 2], o2);
            atomicMax(&nmax[c * 3 + 0], fenc(o0));
            atomicMax(&nmax[c * 3 + 1], fenc(o1));
            atomicMax(&nmax[c * 3 + 2], fenc(o2));
            if (count_flag) atomicAdd(&ncnt[c], 1.0f);
        }
    }
}

// Node MLP: in = [x(7), sum(3), max(3), mean(3), u[batch](2)] (18) -> H=128 -> 7
__global__ __launch_bounds__(256) void node_kernel(
    const float* __restrict__ x_in, const float* __restrict__ nsum,
    const unsigned* __restrict__ nmax, const float* __restrict__ ncnt,
    const float* __restrict__ u, const int* __restrict__ batch,
    const float* __restrict__ W1, const float* __restrict__ b1,
    const float* __restrict__ W2, const float* __restrict__ b2,
    float* __restrict__ x_out, int do_pool,
    float* __restrict__ gsum, unsigned* __restrict__ gmax, float* __restrict__ gcnt)
{
    // row j (28 floats): [W1[0..17][j], b1[j], W2[j][0..6], pad, pad]
    __shared__ __align__(16) float sW[128 * 28];
    int tid = threadIdx.x;
    for (int t = tid; t < 18 * 128; t += 256) { int i = t >> 7, j = t & 127; sW[j * 28 + i] = W1[t]; }
    for (int t = tid; t < 128; t += 256) sW[t * 28 + 18] = b1[t];
    for (int t = tid; t < 128 * 7; t += 256) { int j = t / 7, k = t - j * 7; sW[j * 28 + 19 + k] = W2[t]; }
    __syncthreads();

    float in[NPT][18];
    float acc[NPT][7];
    int ns[NPT];
    int bt[NPT];
    int n0 = blockIdx.x * (256 * NPT) + tid;

    #pragma unroll
    for (int k = 0; k < NPT; ++k) {
        int n = n0 + k * 256;
        ns[k] = n;
        if (n < NN) {
            #pragma unroll
            for (int i = 0; i < 7; ++i) in[k][i] = x_in[n * 7 + i];
            float c = ncnt[n];
            #pragma unroll
            for (int i = 0; i < 3; ++i) {
                float s = nsum[n * 3 + i];
                in[k][7 + i] = s;
                in[k][10 + i] = (c > 0.f) ? fdec(nmax[n * 3 + i]) : 0.f;
                in[k][13 + i] = s / fmaxf(c, 1.f);
            }
            int b = batch[n];
            bt[k] = b;
            in[k][16] = u[b * 2 + 0];
            in[k][17] = u[b * 2 + 1];
        } else {
            bt[k] = 0;
            #pragma unroll
            for (int i = 0; i < 18; ++i) in[k][i] = 0.f;
        }
        #pragma unroll
        for (int c = 0; c < 7; ++c) acc[k][c] = 0.f;
    }

    for (int j = 0; j < 128; ++j) {
        float4 w0 = *(const float4*)&sW[j * 28 + 0];
        float4 w1 = *(const float4*)&sW[j * 28 + 4];
        float4 w2 = *(const float4*)&sW[j * 28 + 8];
        float4 w3 = *(const float4*)&sW[j * 28 + 12];
        float4 w4 = *(const float4*)&sW[j * 28 + 16]; // in16, in17, b1, w2_0
        float4 w5 = *(const float4*)&sW[j * 28 + 20]; // w2_1..w2_4
        float4 w6 = *(const float4*)&sW[j * 28 + 24]; // w2_5, w2_6, pad, pad
        #pragma unroll
        for (int k = 0; k < NPT; ++k) {
            float h = w4.z;
            h += in[k][0] * w0.x;  h += in[k][1] * w0.y;  h += in[k][2] * w0.z;  h += in[k][3] * w0.w;
            h += in[k][4] * w1.x;  h += in[k][5] * w1.y;  h += in[k][6] * w1.z;  h += in[k][7] * w1.w;
            h += in[k][8] * w2.x;  h += in[k][9] * w2.y;  h += in[k][10] * w2.z; h += in[k][11] * w2.w;
            h += in[k][12] * w3.x; h += in[k][13] * w3.y; h += in[k][14] * w3.z; h += in[k][15] * w3.w;
            h += in[k][16] * w4.x; h += in[k][17] * w4.y;
            h = fmaxf(h, 0.f);
            acc[k][0] += h * w4.w; acc[k][1] += h * w5.x; acc[k][2] += h * w5.y;
            acc[k][3] += h * w5.z; acc[k][4] += h * w5.w; acc[k][5] += h * w6.x;
            acc[k][6] += h * w6.y;
        }
    }

    float bb[7];
    #pragma unroll
    for (int c = 0; c < 7; ++c) bb[c] = b2[c];

    #pragma unroll
    for (int k = 0; k < NPT; ++k) {
        int n = ns[k];
        if (n < NN) {
            #pragma unroll
            for (int c = 0; c < 7; ++c) {
                float o = acc[k][c] + bb[c];
                x_out[n * 7 + c] = o;
                if (do_pool) {
                    atomicAdd(&gsum[bt[k] * 7 + c], o);
                    atomicMax(&gmax[bt[k] * 7 + c], fenc(o));
                }
            }
            if (do_pool) atomicAdd(&gcnt[bt[k]], 1.0f);
        }
    }
}

// Output head: per graph g: in = [sum(7), mean(7), max(7), u(2)] (23)
// -> relu H -> relu H -> relu H -> 1
__global__ __launch_bounds__(128) void head_kernel(
    const float* __restrict__ gsum, const unsigned* __restrict__ gmax,
    const float* __restrict__ gcnt, const float* __restrict__ u,
    const float* __restrict__ oW1, const float* __restrict__ ob1,
    const float* __restrict__ oW2, const float* __restrict__ ob2,
    const float* __restrict__ oW3, const float* __restrict__ ob3,
    const float* __restrict__ oW4, const float* __restrict__ ob4,
    float* __restrict__ out)
{
    int g = blockIdx.x, j = threadIdx.x;
    __shared__ float hin[23];
    __shared__ float ha[128];
    __shared__ float hb[128];
    if (j < 7) {
        float s = gsum[g * 7 + j];
        float c = gcnt[g];
        hin[j] = s;
        hin[7 + j] = s / fmaxf(c, 1.f);
        hin[14 + j] = (c > 0.f) ? fdec(gmax[g * 7 + j]) : 0.f;
    }
    if (j < 2) hin[21 + j] = u[g * 2 + j];
    __syncthreads();

    float h = ob1[j];
    for (int i = 0; i < 23; ++i) h += hin[i] * oW1[i * 128 + j];
    h = fmaxf(h, 0.f);
    ha[j] = h;
    __syncthreads();

    h = ob2[j];
    for (int i = 0; i < 128; ++i) h += ha[i] * oW2[i * 128 + j];
    h = fmaxf(h, 0.f);
    hb[j] = h;
    __syncthreads();

    h = ob3[j];
    for (int i = 0; i < 128; ++i) h += hb[i] * oW3[i * 128 + j];
    h = fmaxf(h, 0.f);
    ha[j] = h * oW4[j];
    __syncthreads();

    if (j == 0) {
        float s = ob4[0];
        for (int i = 0; i < 128; ++i) s += ha[i];
        out[g] = s;
    }
}

extern "C" void kernel_launch(void* const* d_in, const int* in_sizes, int n_in,
                              void* d_out, int out_size, void* d_ws, size_t ws_size,
                              hipStream_t stream) {
    const float* x         = (const float*)d_in[0];
    const float* edge_attr = (const float*)d_in[1];
    const float* u         = (const float*)d_in[2];
    const float* eW1 = (const float*)d_in[3];
    const float* eb1 = (const float*)d_in[4];
    const float* eW2 = (const float*)d_in[5];
    const float* eb2 = (const float*)d_in[6];
    const float* nW1 = (const float*)d_in[7];
    const float* nb1 = (const float*)d_in[8];
    const float* nW2 = (const float*)d_in[9];
    const float* nb2 = (const float*)d_in[10];
    const float* oW1 = (const float*)d_in[11];
    const float* ob1 = (const float*)d_in[12];
    const float* oW2 = (const float*)d_in[13];
    const float* ob2 = (const float*)d_in[14];
    const float* oW3 = (const float*)d_in[15];
    const float* ob3 = (const float*)d_in[16];
    const float* oW4 = (const float*)d_in[17];
    const float* ob4 = (const float*)d_in[18];
    const int* edge_index = (const int*)d_in[19];
    const int* batch      = (const int*)d_in[20];
    const int* row = edge_index;
    const int* col = edge_index + NE;

    float* ws    = (float*)d_ws;
    float* ws_e  = ws;                                  // E*3
    float* ws_x  = ws_e + (size_t)NE * 3;               // N*7
    float* nsum  = ws_x + (size_t)NN * 7;               // N*3
    unsigned* nmax = (unsigned*)(nsum + (size_t)NN * 3);// N*3
    float* ncnt  = (float*)(nmax + (size_t)NN * 3);     // N
    float* gsum  = ncnt + NN;                           // G*7
    unsigned* gmax = (unsigned*)(gsum + NG * 7);        // G*7
    float* gcnt  = (float*)(gmax + NG * 7);             // G

    // zero node accumulators (sum+max+cnt = 7N floats) and graph accums (15G)
    {
        int n = NN * 7;
        zero_kernel<<<(n + 255) / 256, 256, 0, stream>>>(nsum, n);
        int m = NG * 15;
        zero_kernel<<<(m + 255) / 256, 256, 0, stream>>>(gsum, m);
    }

    dim3 eb(256), eg((NE + 256 * EPT - 1) / (256 * EPT));
    dim3 nb(256), ng((NN + 256 * NPT - 1) / (256 * NPT));

    // ---- layer 0 ----
    edge_kernel<<<eg, eb, 0, stream>>>(x, edge_attr, ws_e, row, col,
        eW1, eb1, eW2, eb2, nsum, nmax, ncnt, 1);
    node_kernel<<<ng, nb, 0, stream>>>(x, nsum, nmax, ncnt, u, batch,
        nW1, nb1, nW2, nb2, ws_x, 0, gsum, gmax, gcnt);

    // ---- layer 1 ----
    {
        int n = NN * 6; // re-zero nsum + nmax, keep ncnt (same col distribution)
        zero_kernel<<<(n + 255) / 256, 256, 0, stream>>>(nsum, n);
    }
    edge_kernel<<<eg, eb, 0, stream>>>(ws_x, ws_e, ws_e, row, col,
        eW1 + 17 * 128, eb1 + 128, eW2 + 128 * 3, eb2 + 3, nsum, nmax, ncnt, 0);
    node_kernel<<<ng, nb, 0, stream>>>(ws_x, nsum, nmax, ncnt, u, batch,
        nW1 + 18 * 128, nb1 + 128, nW2 + 128 * 7, nb2 + 7, ws_x, 1, gsum, gmax, gcnt);

    // ---- head ----
    head_kernel<<<NG, 128, 0, stream>>>(gsum, gmax, gcnt, u,
        oW1, ob1, oW2, ob2, oW3, ob3, oW4, ob4, (float*)d_out);
}